// Round 4
// baseline (490.091 us; speedup 1.0000x reference)
//
#include <hip/hip_runtime.h>

// LaminiIndex v9: out_k = softmax(Q K^T) K, out_v = softmax(Q K^T) V
// Q: 4096x128 fp32, K/V: 65536x128 fp32, outputs fp32 concat.
//
// v8: depth-2 P pipeline, barrier per 2 iters. attn 215us, MfmaUtil 43%.
//   Three structural rounds each bought ~2% => lockstep/barrier theories
//   dead. Cycle model: MFMA 1536 / LDS ~1700 / L1 1536 / VALU 1000 per
//   CU-iter of 4040 => bottleneck is UNHIDDEN LATENCY inside each wave.
//   SQ_LDS_BANK_CONFLICT (2.1e7, invariant) = b128 inherent cost, not
//   swizzle-fixable.
// v9: hoist PV ds_reads. P_t is in LDS at iter start (depth-2), so issue
//   kk=0,1 A-frag reads (8x b128) FIRST in the iteration -- before the
//   VMEM prefetch burst and the 8-MFMA S cluster (~400+cy cover) -- and
//   refill each freed buffer with kk+2 right after its MFMA group
//   (rolling 2-ahead). Kills the per-kk read->lgkm->MFMA serial chains.
//   +32 VGPR (~224 total incl AGPR, still 2 waves/SIMD).

typedef _Float16 f16x8  __attribute__((ext_vector_type(8)));
typedef short    s16x8  __attribute__((ext_vector_type(8)));
typedef float    f32x16 __attribute__((ext_vector_type(16)));

#define M_TOTAL 4096
#define N_TOTAL 65536
#define DDIM    128
#define BM      128
#define BN      64

__device__ __forceinline__ unsigned int bf16_rne(float x) {
    unsigned int u = __float_as_uint(x);
    u += 0x7FFFu + ((u >> 16) & 1u);
    return u >> 16;
}

// One 64-key tile per block. K-blocks (bid<1024) write Kfp (S A-frags, f16)
// + KTp (O B-frags, bf16); V-blocks write VTp.
// Fragment order (32x32x16): A[m][k]: m=lane&31, k=8*(lane>>5)+j.
//                            B[k][n]: n=lane&31, k=8*(lane>>5)+j.
// Kfp slot c = (kb*8+kk)*64+lane  -> K[t*64+kb*32+(lane&31)][kk*16+8h+j]
// Tp  slot c = (dn*4+kk)*64+lane  -> X[t*64+kk*16+8h+j][dn*32+(lane&31)]
__global__ void prep_kernel(const float* __restrict__ K, const float* __restrict__ V,
                            _Float16* __restrict__ Kfp,
                            unsigned short* __restrict__ KTp,
                            unsigned short* __restrict__ VTp) {
    __shared__ float tile[64 * 132];
    const int bid = blockIdx.x;
    const int isV = bid >> 10;
    const int t   = bid & 1023;
    const float* src = isV ? V : K;
    const int tid = threadIdx.x;
#pragma unroll
    for (int k = 0; k < 8; ++k) {                   // 64x128 fp32 in, coalesced
        int c   = tid + 256 * k;
        int row = c >> 5;
        int c4  = c & 31;
        float4 v = *(const float4*)(src + (size_t)(t * 64 + row) * DDIM + c4 * 4);
        *(float4*)&tile[row * 132 + c4 * 4] = v;
    }
    __syncthreads();

    unsigned short* Tp = isV ? VTp : KTp;
#pragma unroll
    for (int r = 0; r < 4; ++r) {                   // B-frags: 1024 slots x 16B
        int c   = tid + 256 * r;
        int ln  = c & 63;
        int l31 = ln & 31, h = ln >> 5;
        int dn  = c >> 8;
        int kk  = (c >> 6) & 3;
        int col = dn * 32 + l31;                    // d
        int k0  = kk * 16 + h * 8;                  // key base
        uint4 o;
        o.x = bf16_rne(tile[(k0 + 0) * 132 + col]) | (bf16_rne(tile[(k0 + 1) * 132 + col]) << 16);
        o.y = bf16_rne(tile[(k0 + 2) * 132 + col]) | (bf16_rne(tile[(k0 + 3) * 132 + col]) << 16);
        o.z = bf16_rne(tile[(k0 + 4) * 132 + col]) | (bf16_rne(tile[(k0 + 5) * 132 + col]) << 16);
        o.w = bf16_rne(tile[(k0 + 6) * 132 + col]) | (bf16_rne(tile[(k0 + 7) * 132 + col]) << 16);
        *(uint4*)(Tp + ((size_t)t * 1024 + c) * 8) = o;
    }
    if (!isV) {
#pragma unroll
        for (int r = 0; r < 4; ++r) {               // A-frags: 1024 slots x 16B
            int c   = tid + 256 * r;
            int ln  = c & 63;
            int l31 = ln & 31, h = ln >> 5;
            int kb  = c >> 9;
            int kk  = (c >> 6) & 7;
            int row = kb * 32 + l31;                // key
            int d0  = kk * 16 + h * 8;
            f16x8 f;
#pragma unroll
            for (int j = 0; j < 8; ++j) f[j] = (_Float16)tile[row * 132 + d0 + j];
            *(f16x8*)(Kfp + ((size_t)t * 1024 + c) * 8) = f;
        }
    }
}

// exp(s-100) for 4 S values, pack to bf16 (RNE via v_cvt_pk), store 8B to LDS.
// l_loc accumulates the fp32 partial denominator.
__device__ __forceinline__ void softmax4(float s0, float s1, float s2, float s3,
                                         unsigned short* dst, float& l_loc) {
    const float L2E = 1.4426950408889634f;
    const float SH  = -144.26950408889634f;         // -100 * log2(e)
    float x0 = __builtin_fmaf(s0, L2E, SH);
    float x1 = __builtin_fmaf(s1, L2E, SH);
    float x2 = __builtin_fmaf(s2, L2E, SH);
    float x3 = __builtin_fmaf(s3, L2E, SH);
    float p0, p1, p2, p3;
    asm("v_exp_f32 %0, %1" : "=v"(p0) : "v"(x0));
    asm("v_exp_f32 %0, %1" : "=v"(p1) : "v"(x1));
    asm("v_exp_f32 %0, %1" : "=v"(p2) : "v"(x2));
    asm("v_exp_f32 %0, %1" : "=v"(p3) : "v"(x3));
    l_loc += (p0 + p1) + (p2 + p3);
    unsigned int r0, r1;
    asm("v_cvt_pk_bf16_f32 %0, %1, %2" : "=v"(r0) : "v"(p0), "v"(p1));
    asm("v_cvt_pk_bf16_f32 %0, %1, %2" : "=v"(r1) : "v"(p2), "v"(p3));
    uint2 pk; pk.x = r0; pk.y = r1;
    *(uint2*)dst = pk;
}

// One pipeline stage (iter t): hoisted PV ds_reads (kk=0,1), VMEM prefetch
// A(t+3)/B(t+1), S_{t+2} (two chains), then per-kk {PV MFMA, refill kk+2
// reads, softmax_{t+2} group}. pr/pw compile-time distinct at call sites.
__device__ __forceinline__ void attn_iter(
    const _Float16* __restrict__ Ap, const unsigned short* __restrict__ Bp,
    size_t ta, size_t tb,
    f16x8 (&af)[8], s16x8 (&bfu)[4],
    f16x8 (&afn)[8], s16x8 (&bfn)[4],
    const f16x8 (&qf)[8],
    const unsigned short* __restrict__ pr, unsigned short* __restrict__ pw,
    int l31, int h, int x7, int kb, float& l_loc, f32x16 (&acc)[4])
{
    // PV A-frag reads, rolling 2 chunks ahead. First pair issued before
    // everything else: S cluster + VMEM burst (~400+cy) hide the latency.
    s16x8 ap0[4], ap1[4];
    {
        const int ch0 = ((0 + h) ^ x7) << 3;
        const int ch1 = ((2 + h) ^ x7) << 3;
#pragma unroll
        for (int qm = 0; qm < 4; ++qm)
            ap0[qm] = *(const s16x8*)&pr[(qm * 32 + l31) * 64 + ch0];
#pragma unroll
        for (int qm = 0; qm < 4; ++qm)
            ap1[qm] = *(const s16x8*)&pr[(qm * 32 + l31) * 64 + ch1];
    }

    // Next-tile global prefetch (consumed next iteration).
#pragma unroll
    for (int kk = 0; kk < 8; ++kk) afn[kk] = *(const f16x8*)(Ap + ta + kk * 512);
#pragma unroll
    for (int kk = 0; kk < 4; ++kk) bfn[kk] = *(const s16x8*)(Bp + tb + kk * 512);

    // S_{t+2}: two interleaved dependency chains (halves serial latency).
    f32x16 s0 = 0.f, s1 = 0.f;
    __builtin_amdgcn_s_setprio(1);
#pragma unroll
    for (int p = 0; p < 4; ++p) {
        s0 = __builtin_amdgcn_mfma_f32_32x32x16_f16(af[2 * p],     qf[2 * p],     s0, 0, 0, 0);
        s1 = __builtin_amdgcn_mfma_f32_32x32x16_f16(af[2 * p + 1], qf[2 * p + 1], s1, 0, 0, 0);
    }
    __builtin_amdgcn_s_setprio(0);
    f32x16 sn = s0 + s1;

#pragma unroll
    for (int kk = 0; kk < 4; ++kk) {
        s16x8* apc = (kk & 1) ? ap1 : ap0;          // kk compile-time: static
        __builtin_amdgcn_s_setprio(1);
#pragma unroll
        for (int qm = 0; qm < 4; ++qm)
            acc[qm] = __builtin_amdgcn_mfma_f32_32x32x16_bf16(apc[qm], bfu[kk], acc[qm], 0, 0, 0);
        __builtin_amdgcn_s_setprio(0);
        if (kk < 2) {                               // refill freed buffer w/ kk+2
            const int ch = (((kk + 2) * 2 + h) ^ x7) << 3;
#pragma unroll
            for (int qm = 0; qm < 4; ++qm)
                apc[qm] = *(const s16x8*)&pr[(qm * 32 + l31) * 64 + ch];
        }
        // softmax_{t+2} group kk (independent of the PV above -> co-issue).
        // C layout: col=l31 (q), row=(r&3)+8*(r>>2)+4h (key in kb*32 block).
        softmax4(sn[4 * kk + 0], sn[4 * kk + 1], sn[4 * kk + 2], sn[4 * kk + 3],
                 pw + (((kb * 4 + kk) ^ x7) << 3), l_loc);
    }
}

// grid ns*32 (1-D), 512 thr. split = bid & (ns-1) -> same-XCD blocks share a
// key stream (L2 locality). Block: 128 queries x (1024/ns) 64-key tiles.
__global__ __launch_bounds__(512, 2)
void attn_kernel(const float* __restrict__ Q, const _Float16* __restrict__ Kfp,
                 const unsigned short* __restrict__ KTp, const unsigned short* __restrict__ VTp,
                 float* __restrict__ Okp, float* __restrict__ Ovp, float* __restrict__ Lp,
                 int iters, int nsm1, int nslog) {
    __shared__ unsigned short p_lds[4][BM * BN];    // P_t at buffer t&3, XOR-swizzled
    __shared__ float l_red[2][BM];

    const int bid   = blockIdx.x;
    const int split = bid & nsm1;
    const int q0    = (bid >> nslog) * BM;
    const int tid   = threadIdx.x;
    const int w     = tid >> 6;
    const int lane  = tid & 63;
    const int l31   = lane & 31;
    const int h     = lane >> 5;
    const int kb  = w & 1,  qb = w >> 1;            // S roles: key-half, q-quarter
    const int mat = w & 1,  dn = w >> 1;            // O roles: K/V, d-quarter

    // Q B-frags (loop-invariant): qf[kk][j] = Q[q0+qb*32+l31][kk*16+8h+j], f16.
    f16x8 qf[8];
    {
        const float* qrow = Q + (size_t)(q0 + qb * 32 + l31) * DDIM + h * 8;
#pragma unroll
        for (int kk = 0; kk < 8; ++kk) {
            float4 a = *(const float4*)(qrow + kk * 16);
            float4 b = *(const float4*)(qrow + kk * 16 + 4);
            f16x8 f;
            f[0] = (_Float16)a.x; f[1] = (_Float16)a.y; f[2] = (_Float16)a.z; f[3] = (_Float16)a.w;
            f[4] = (_Float16)b.x; f[5] = (_Float16)b.y; f[6] = (_Float16)b.z; f[7] = (_Float16)b.w;
            qf[kk] = f;
        }
    }

    const unsigned short* Tp = mat ? VTp : KTp;
    const _Float16*       Ap = Kfp + ((size_t)(kb * 8) * 64 + lane) * 8;   // + t*8192 + kk*512
    const unsigned short* Bp = Tp  + ((size_t)(dn * 4) * 64 + lane) * 8;   // + t*8192 + kk*512

    f32x16 acc[4];                                  // O: q128 x d32, one matrix
#pragma unroll
    for (int qm = 0; qm < 4; ++qm) acc[qm] = 0.f;
    float l_loc = 0.f;

    const int t0  = split * iters;
    const int x7  = l31 & 7;
    const int qrl = qb * 32 + l31;

    unsigned short* const pbase  = &p_lds[0][0];
    unsigned short* const pwbase = pbase + qrl * 64 + h * 4;   // + buf*8192 + chunk

    // ---- prologue: tiles t0, t0+1: S + softmax -> buf0, buf1 ----
    f16x8 afA[8], afB[8]; s16x8 bfA[4], bfB[4];
#pragma unroll
    for (int kk = 0; kk < 8; ++kk) afA[kk] = *(const f16x8*)(Ap + (size_t)t0 * 8192 + kk * 512);
    {
        f32x16 s0 = 0.f, s1 = 0.f;
#pragma unroll
        for (int p = 0; p < 4; ++p) {
            s0 = __builtin_amdgcn_mfma_f32_32x32x16_f16(afA[2 * p],     qf[2 * p],     s0, 0, 0, 0);
            s1 = __builtin_amdgcn_mfma_f32_32x32x16_f16(afA[2 * p + 1], qf[2 * p + 1], s1, 0, 0, 0);
        }
        // B(t0) + A(t0+1): issue before softmax so latency hides under VALU.
#pragma unroll
        for (int kk = 0; kk < 4; ++kk) bfA[kk] = *(const s16x8*)(Bp + (size_t)t0 * 8192 + kk * 512);
#pragma unroll
        for (int kk = 0; kk < 8; ++kk) afB[kk] = *(const f16x8*)(Ap + (size_t)(t0 + 1) * 8192 + kk * 512);
        f32x16 sa = s0 + s1;
#pragma unroll
        for (int g = 0; g < 4; ++g)
            softmax4(sa[4 * g + 0], sa[4 * g + 1], sa[4 * g + 2], sa[4 * g + 3],
                     pwbase + (((kb * 4 + g) ^ x7) << 3), l_loc);
    }
    {
        // S(t0+1) from afB; then prefetch A(t0+2) into afA for iter 0.
        f32x16 s0 = 0.f, s1 = 0.f;
#pragma unroll
        for (int p = 0; p < 4; ++p) {
            s0 = __builtin_amdgcn_mfma_f32_32x32x16_f16(afB[2 * p],     qf[2 * p],     s0, 0, 0, 0);
            s1 = __builtin_amdgcn_mfma_f32_32x32x16_f16(afB[2 * p + 1], qf[2 * p + 1], s1, 0, 0, 0);
        }
#pragma unroll
        for (int kk = 0; kk < 8; ++kk) afA[kk] = *(const f16x8*)(Ap + (size_t)(t0 + 2) * 8192 + kk * 512);
        f32x16 sb = s0 + s1;
#pragma unroll
        for (int g = 0; g < 4; ++g)
            softmax4(sb[4 * g + 0], sb[4 * g + 1], sb[4 * g + 2], sb[4 * g + 3],
                     pwbase + 8192 + (((kb * 4 + g) ^ x7) << 3), l_loc);
    }
    __syncthreads();

    // ---- main loop: body count iters-2 (even). Iter it: af=A(it+2),
    // bf=B(it); loads A(it+3), B(it+1); reads P_it (buf it&3), writes
    // P_{it+2} (buf (it+2)&3). Barrier every 2 iters: produce->consume
    // distance 2 and buffer-reuse distance 4 both span >=1 barrier.
    const int npair = (iters - 2) >> 1;
    for (int p2 = 0; p2 < npair; ++p2) {
        const int it = p2 * 2;
        const int b  = (p2 & 1) << 1;               // it&3
        attn_iter(Ap, Bp, (size_t)(t0 + it + 3) * 8192, (size_t)(t0 + it + 1) * 8192,
                  afA, bfA, afB, bfB, qf,
                  pbase + (b << 13), pwbase + ((b ^ 2) << 13),
                  l31, h, x7, kb, l_loc, acc);
        attn_iter(Ap, Bp, (size_t)(t0 + it + 4) * 8192, (size_t)(t0 + it + 2) * 8192,
                  afB, bfB, afA, bfA, qf,
                  pbase + ((b ^ 1) << 13), pwbase + ((b ^ 3) << 13),
                  l31, h, x7, kb, l_loc, acc);
        __syncthreads();
    }
    // Note: the very last pair's A-prefetch reads tile t0+iters, which for
    // the last split overruns Kfp into KTp (valid memory, values unused).

    // ---- epilogue: PV for tiles iters-2 (bfA) and iters-1 (fresh load).
    // Both P-buffers were written before the final loop barrier.
    {
        s16x8 bfL[4];
#pragma unroll
        for (int kk = 0; kk < 4; ++kk)
            bfL[kk] = *(const s16x8*)(Bp + (size_t)(t0 + iters - 1) * 8192 + kk * 512);

        const unsigned short* pr2 = pbase + (size_t)(((iters - 2) & 3) << 13);
#pragma unroll
        for (int kk = 0; kk < 4; ++kk) {
            s16x8 ap[4];
            const int ch = ((kk * 2 + h) ^ x7) << 3;
#pragma unroll
            for (int qm = 0; qm < 4; ++qm)
                ap[qm] = *(const s16x8*)&pr2[(qm * 32 + l31) * 64 + ch];
#pragma unroll
            for (int qm = 0; qm < 4; ++qm)
                acc[qm] = __builtin_amdgcn_mfma_f32_32x32x16_bf16(ap[qm], bfA[kk], acc[qm], 0, 0, 0);
        }
        const unsigned short* pr3 = pbase + (size_t)(((iters - 1) & 3) << 13);
#pragma unroll
        for (int kk = 0; kk < 4; ++kk) {
            s16x8 ap[4];
            const int ch = ((kk * 2 + h) ^ x7) << 3;
#pragma unroll
            for (int qm = 0; qm < 4; ++qm)
                ap[qm] = *(const s16x8*)&pr3[(qm * 32 + l31) * 64 + ch];
#pragma unroll
            for (int qm = 0; qm < 4; ++qm)
                acc[qm] = __builtin_amdgcn_mfma_f32_32x32x16_bf16(ap[qm], bfL[kk], acc[qm], 0, 0, 0);
        }
    }

    // L partial: halves of each 32-key block via shfl, kb-fold via LDS.
    l_loc += __shfl_xor(l_loc, 32, 64);
    if (h == 0) l_red[kb][qb * 32 + l31] = l_loc;
    __syncthreads();
    if (tid < BM)
        Lp[(size_t)split * M_TOTAL + q0 + tid] = l_red[0][tid] + l_red[1][tid];

    // O partial: C/D col=l31 (d), row=(r&3)+8*(r>>2)+4h (q in qm*32 block).
    float* ob = (mat ? Ovp : Okp) + (size_t)split * (M_TOTAL * DDIM);
#pragma unroll
    for (int qm = 0; qm < 4; ++qm)
#pragma unroll
        for (int r = 0; r < 16; ++r) {
            int q = q0 + qm * 32 + (r & 3) + 8 * (r >> 2) + 4 * h;
            ob[(size_t)q * DDIM + dn * 32 + l31] = acc[qm][r];
        }
}

__global__ void combine_kernel(const float* __restrict__ Okp, const float* __restrict__ Ovp,
                               const float* __restrict__ Lp, float* __restrict__ out, int ns) {
    int i4 = blockIdx.x * 256 + threadIdx.x;        // float4 index, 131072 total
    int q  = i4 >> 5;
    float L = 0.f;
    float4 sk = make_float4(0.f, 0.f, 0.f, 0.f);
    float4 sv = make_float4(0.f, 0.f, 0.f, 0.f);
    for (int s = 0; s < ns; ++s) {
        L += Lp[(size_t)s * M_TOTAL + q];
        float4 a = ((const float4*)Okp)[(size_t)s * 131072 + i4];
        float4 b = ((const float4*)Ovp)[(size_t)s * 131072 + i4];
        sk.x += a.x; sk.y += a.y; sk.z += a.z; sk.w += a.w;
        sv.x += b.x; sv.y += b.y; sv.z += b.z; sv.w += b.w;
    }
    float inv = 1.f / L;
    float4 ok = make_float4(sk.x * inv, sk.y * inv, sk.z * inv, sk.w * inv);
    float4 ov = make_float4(sv.x * inv, sv.y * inv, sv.z * inv, sv.w * inv);
    ((float4*)out)[i4]          = ok;               // key_vectors
    ((float4*)out)[131072 + i4] = ov;               // value_vectors
}

extern "C" void kernel_launch(void* const* d_in, const int* in_sizes, int n_in,
                              void* d_out, int out_size, void* d_ws, size_t ws_size,
                              hipStream_t stream) {
    const float* Q = (const float*)d_in[0];
    const float* K = (const float*)d_in[1];
    const float* V = (const float*)d_in[2];
    float* out = (float*)d_out;

    // ws: Kfp 16MiB | KTp 16MiB | VTp 16MiB | Lp ns*16KB | Okp ns*2MiB | Ovp ns*2MiB
    const size_t MB = 1024 * 1024;
    int ns = 8, nslog = 3;
    while (ns > 2) {
        size_t need = 48 * MB + (size_t)ns * (4 * MB + 16384);
        if (need <= ws_size) break;
        ns >>= 1; nslog -= 1;
    }
    char* w0 = (char*)d_ws;
    _Float16*       Kfp = (_Float16*)w0;
    unsigned short* KTp = (unsigned short*)(w0 + 16 * MB);
    unsigned short* VTp = (unsigned short*)(w0 + 32 * MB);
    float*          Lp  = (float*)(w0 + 48 * MB);
    float*          Okp = (float*)(w0 + 48 * MB + (size_t)ns * 16384);
    float*          Ovp = Okp + (size_t)ns * (M_TOTAL * DDIM);

    prep_kernel<<<2048, 256, 0, stream>>>(K, V, Kfp, KTp, VTp);

    const int iters = 1024 / ns;                    // 64-key tiles per split
    attn_kernel<<<ns * 32, 512, 0, stream>>>(Q, Kfp, KTp, VTp, Okp, Ovp, Lp,
                                             iters, ns - 1, nslog);
    combine_kernel<<<(M_TOTAL * DDIM / 4) / 256, 256, 0, stream>>>(Okp, Ovp, Lp, out, ns);
}

// Round 5
// 364.233 us; speedup vs baseline: 1.3455x; 1.3455x over previous
//
#include <hip/hip_runtime.h>

// LaminiIndex v10: out_k = softmax(Q K^T) K, out_v = softmax(Q K^T) V
// Q: 4096x128 fp32, K/V: 65536x128 fp32, outputs fp32 concat.
//
// v8 (best, 215us attn): depth-2 P pipeline, barrier per 2 iters,
//   MfmaUtil 43%.
// v9 (FAILED, 420us): hoisted PV ds_reads via `s16x8* apc = kk&1 ? ap1:ap0`
//   -- runtime pointer into local arrays defeats SROA (rule #20), ap0/ap1
//   went to scratch: WRITE_SIZE 36->341MB. Theory never tested.
// v10: same hoist, NO pointer indirection. PV written as 4 explicit phases
//   on named arrays ap0/ap1 (constant indices only): kk=0,1 reads at iter
//   top (covered by VMEM burst + 8-MFMA S cluster), refill with kk+2 after
//   each MFMA group. Otherwise byte-for-byte v8.

typedef _Float16 f16x8  __attribute__((ext_vector_type(8)));
typedef short    s16x8  __attribute__((ext_vector_type(8)));
typedef float    f32x16 __attribute__((ext_vector_type(16)));

#define M_TOTAL 4096
#define N_TOTAL 65536
#define DDIM    128
#define BM      128
#define BN      64

__device__ __forceinline__ unsigned int bf16_rne(float x) {
    unsigned int u = __float_as_uint(x);
    u += 0x7FFFu + ((u >> 16) & 1u);
    return u >> 16;
}

// One 64-key tile per block. K-blocks (bid<1024) write Kfp (S A-frags, f16)
// + KTp (O B-frags, bf16); V-blocks write VTp.
// Fragment order (32x32x16): A[m][k]: m=lane&31, k=8*(lane>>5)+j.
//                            B[k][n]: n=lane&31, k=8*(lane>>5)+j.
// Kfp slot c = (kb*8+kk)*64+lane  -> K[t*64+kb*32+(lane&31)][kk*16+8h+j]
// Tp  slot c = (dn*4+kk)*64+lane  -> X[t*64+kk*16+8h+j][dn*32+(lane&31)]
__global__ void prep_kernel(const float* __restrict__ K, const float* __restrict__ V,
                            _Float16* __restrict__ Kfp,
                            unsigned short* __restrict__ KTp,
                            unsigned short* __restrict__ VTp) {
    __shared__ float tile[64 * 132];
    const int bid = blockIdx.x;
    const int isV = bid >> 10;
    const int t   = bid & 1023;
    const float* src = isV ? V : K;
    const int tid = threadIdx.x;
#pragma unroll
    for (int k = 0; k < 8; ++k) {                   // 64x128 fp32 in, coalesced
        int c   = tid + 256 * k;
        int row = c >> 5;
        int c4  = c & 31;
        float4 v = *(const float4*)(src + (size_t)(t * 64 + row) * DDIM + c4 * 4);
        *(float4*)&tile[row * 132 + c4 * 4] = v;
    }
    __syncthreads();

    unsigned short* Tp = isV ? VTp : KTp;
#pragma unroll
    for (int r = 0; r < 4; ++r) {                   // B-frags: 1024 slots x 16B
        int c   = tid + 256 * r;
        int ln  = c & 63;
        int l31 = ln & 31, h = ln >> 5;
        int dn  = c >> 8;
        int kk  = (c >> 6) & 3;
        int col = dn * 32 + l31;                    // d
        int k0  = kk * 16 + h * 8;                  // key base
        uint4 o;
        o.x = bf16_rne(tile[(k0 + 0) * 132 + col]) | (bf16_rne(tile[(k0 + 1) * 132 + col]) << 16);
        o.y = bf16_rne(tile[(k0 + 2) * 132 + col]) | (bf16_rne(tile[(k0 + 3) * 132 + col]) << 16);
        o.z = bf16_rne(tile[(k0 + 4) * 132 + col]) | (bf16_rne(tile[(k0 + 5) * 132 + col]) << 16);
        o.w = bf16_rne(tile[(k0 + 6) * 132 + col]) | (bf16_rne(tile[(k0 + 7) * 132 + col]) << 16);
        *(uint4*)(Tp + ((size_t)t * 1024 + c) * 8) = o;
    }
    if (!isV) {
#pragma unroll
        for (int r = 0; r < 4; ++r) {               // A-frags: 1024 slots x 16B
            int c   = tid + 256 * r;
            int ln  = c & 63;
            int l31 = ln & 31, h = ln >> 5;
            int kb  = c >> 9;
            int kk  = (c >> 6) & 7;
            int row = kb * 32 + l31;                // key
            int d0  = kk * 16 + h * 8;
            f16x8 f;
#pragma unroll
            for (int j = 0; j < 8; ++j) f[j] = (_Float16)tile[row * 132 + d0 + j];
            *(f16x8*)(Kfp + ((size_t)t * 1024 + c) * 8) = f;
        }
    }
}

// exp(s-100) for 4 S values, pack to bf16 (RNE via v_cvt_pk), store 8B to LDS.
// l_loc accumulates the fp32 partial denominator.
__device__ __forceinline__ void softmax4(float s0, float s1, float s2, float s3,
                                         unsigned short* dst, float& l_loc) {
    const float L2E = 1.4426950408889634f;
    const float SH  = -144.26950408889634f;         // -100 * log2(e)
    float x0 = __builtin_fmaf(s0, L2E, SH);
    float x1 = __builtin_fmaf(s1, L2E, SH);
    float x2 = __builtin_fmaf(s2, L2E, SH);
    float x3 = __builtin_fmaf(s3, L2E, SH);
    float p0, p1, p2, p3;
    asm("v_exp_f32 %0, %1" : "=v"(p0) : "v"(x0));
    asm("v_exp_f32 %0, %1" : "=v"(p1) : "v"(x1));
    asm("v_exp_f32 %0, %1" : "=v"(p2) : "v"(x2));
    asm("v_exp_f32 %0, %1" : "=v"(p3) : "v"(x3));
    l_loc += (p0 + p1) + (p2 + p3);
    unsigned int r0, r1;
    asm("v_cvt_pk_bf16_f32 %0, %1, %2" : "=v"(r0) : "v"(p0), "v"(p1));
    asm("v_cvt_pk_bf16_f32 %0, %1, %2" : "=v"(r1) : "v"(p2), "v"(p3));
    uint2 pk; pk.x = r0; pk.y = r1;
    *(uint2*)dst = pk;
}

// One pipeline stage (iter t): hoisted PV ds_reads (kk=0,1) at top, VMEM
// prefetch A(t+3)/B(t+1), S_{t+2} (two chains), then 4 explicit PV phases
// (NO pointer indirection -- constant-indexed named arrays only) each
// followed by refill (kk<2) and its softmax_{t+2} group.
__device__ __forceinline__ void attn_iter(
    const _Float16* __restrict__ Ap, const unsigned short* __restrict__ Bp,
    size_t ta, size_t tb,
    f16x8 (&af)[8], s16x8 (&bfu)[4],
    f16x8 (&afn)[8], s16x8 (&bfn)[4],
    const f16x8 (&qf)[8],
    const unsigned short* __restrict__ pr, unsigned short* __restrict__ pw,
    int l31, int h, int x7, int kb, float& l_loc, f32x16 (&acc)[4])
{
    const int ch0 = ((0 + h) ^ x7) << 3;
    const int ch1 = ((2 + h) ^ x7) << 3;
    const int ch2 = ((4 + h) ^ x7) << 3;
    const int ch3 = ((6 + h) ^ x7) << 3;

    // Hoisted PV A-frag reads kk=0,1: issued before the VMEM burst and the
    // S cluster, so ~400cy of issue/compute covers the lgkm latency.
    s16x8 ap0[4], ap1[4];
#pragma unroll
    for (int qm = 0; qm < 4; ++qm)
        ap0[qm] = *(const s16x8*)&pr[(qm * 32 + l31) * 64 + ch0];
#pragma unroll
    for (int qm = 0; qm < 4; ++qm)
        ap1[qm] = *(const s16x8*)&pr[(qm * 32 + l31) * 64 + ch1];

    // Next-tile global prefetch (consumed next iteration).
#pragma unroll
    for (int kk = 0; kk < 8; ++kk) afn[kk] = *(const f16x8*)(Ap + ta + kk * 512);
#pragma unroll
    for (int kk = 0; kk < 4; ++kk) bfn[kk] = *(const s16x8*)(Bp + tb + kk * 512);

    // S_{t+2}: two interleaved dependency chains (halves serial latency).
    f32x16 s0 = 0.f, s1 = 0.f;
    __builtin_amdgcn_s_setprio(1);
#pragma unroll
    for (int p = 0; p < 4; ++p) {
        s0 = __builtin_amdgcn_mfma_f32_32x32x16_f16(af[2 * p],     qf[2 * p],     s0, 0, 0, 0);
        s1 = __builtin_amdgcn_mfma_f32_32x32x16_f16(af[2 * p + 1], qf[2 * p + 1], s1, 0, 0, 0);
    }
    __builtin_amdgcn_s_setprio(0);
    f32x16 sn = s0 + s1;

    // ---- PV phase 0: consume ap0, refill ap0 <- chunk 2, softmax g0 ----
    __builtin_amdgcn_s_setprio(1);
#pragma unroll
    for (int qm = 0; qm < 4; ++qm)
        acc[qm] = __builtin_amdgcn_mfma_f32_32x32x16_bf16(ap0[qm], bfu[0], acc[qm], 0, 0, 0);
    __builtin_amdgcn_s_setprio(0);
#pragma unroll
    for (int qm = 0; qm < 4; ++qm)
        ap0[qm] = *(const s16x8*)&pr[(qm * 32 + l31) * 64 + ch2];
    softmax4(sn[0], sn[1], sn[2], sn[3],
             pw + (((kb * 4 + 0) ^ x7) << 3), l_loc);

    // ---- PV phase 1: consume ap1, refill ap1 <- chunk 3, softmax g1 ----
    __builtin_amdgcn_s_setprio(1);
#pragma unroll
    for (int qm = 0; qm < 4; ++qm)
        acc[qm] = __builtin_amdgcn_mfma_f32_32x32x16_bf16(ap1[qm], bfu[1], acc[qm], 0, 0, 0);
    __builtin_amdgcn_s_setprio(0);
#pragma unroll
    for (int qm = 0; qm < 4; ++qm)
        ap1[qm] = *(const s16x8*)&pr[(qm * 32 + l31) * 64 + ch3];
    softmax4(sn[4], sn[5], sn[6], sn[7],
             pw + (((kb * 4 + 1) ^ x7) << 3), l_loc);

    // ---- PV phase 2: consume ap0 (chunk 2), softmax g2 ----
    __builtin_amdgcn_s_setprio(1);
#pragma unroll
    for (int qm = 0; qm < 4; ++qm)
        acc[qm] = __builtin_amdgcn_mfma_f32_32x32x16_bf16(ap0[qm], bfu[2], acc[qm], 0, 0, 0);
    __builtin_amdgcn_s_setprio(0);
    softmax4(sn[8], sn[9], sn[10], sn[11],
             pw + (((kb * 4 + 2) ^ x7) << 3), l_loc);

    // ---- PV phase 3: consume ap1 (chunk 3), softmax g3 ----
    __builtin_amdgcn_s_setprio(1);
#pragma unroll
    for (int qm = 0; qm < 4; ++qm)
        acc[qm] = __builtin_amdgcn_mfma_f32_32x32x16_bf16(ap1[qm], bfu[3], acc[qm], 0, 0, 0);
    __builtin_amdgcn_s_setprio(0);
    softmax4(sn[12], sn[13], sn[14], sn[15],
             pw + (((kb * 4 + 3) ^ x7) << 3), l_loc);
}

// grid ns*32 (1-D), 512 thr. split = bid & (ns-1) -> same-XCD blocks share a
// key stream (L2 locality). Block: 128 queries x (1024/ns) 64-key tiles.
__global__ __launch_bounds__(512, 2)
void attn_kernel(const float* __restrict__ Q, const _Float16* __restrict__ Kfp,
                 const unsigned short* __restrict__ KTp, const unsigned short* __restrict__ VTp,
                 float* __restrict__ Okp, float* __restrict__ Ovp, float* __restrict__ Lp,
                 int iters, int nsm1, int nslog) {
    __shared__ unsigned short p_lds[4][BM * BN];    // P_t at buffer t&3, XOR-swizzled
    __shared__ float l_red[2][BM];

    const int bid   = blockIdx.x;
    const int split = bid & nsm1;
    const int q0    = (bid >> nslog) * BM;
    const int tid   = threadIdx.x;
    const int w     = tid >> 6;
    const int lane  = tid & 63;
    const int l31   = lane & 31;
    const int h     = lane >> 5;
    const int kb  = w & 1,  qb = w >> 1;            // S roles: key-half, q-quarter
    const int mat = w & 1,  dn = w >> 1;            // O roles: K/V, d-quarter

    // Q B-frags (loop-invariant): qf[kk][j] = Q[q0+qb*32+l31][kk*16+8h+j], f16.
    f16x8 qf[8];
    {
        const float* qrow = Q + (size_t)(q0 + qb * 32 + l31) * DDIM + h * 8;
#pragma unroll
        for (int kk = 0; kk < 8; ++kk) {
            float4 a = *(const float4*)(qrow + kk * 16);
            float4 b = *(const float4*)(qrow + kk * 16 + 4);
            f16x8 f;
            f[0] = (_Float16)a.x; f[1] = (_Float16)a.y; f[2] = (_Float16)a.z; f[3] = (_Float16)a.w;
            f[4] = (_Float16)b.x; f[5] = (_Float16)b.y; f[6] = (_Float16)b.z; f[7] = (_Float16)b.w;
            qf[kk] = f;
        }
    }

    const unsigned short* Tp = mat ? VTp : KTp;
    const _Float16*       Ap = Kfp + ((size_t)(kb * 8) * 64 + lane) * 8;   // + t*8192 + kk*512
    const unsigned short* Bp = Tp  + ((size_t)(dn * 4) * 64 + lane) * 8;   // + t*8192 + kk*512

    f32x16 acc[4];                                  // O: q128 x d32, one matrix
#pragma unroll
    for (int qm = 0; qm < 4; ++qm) acc[qm] = 0.f;
    float l_loc = 0.f;

    const int t0  = split * iters;
    const int x7  = l31 & 7;
    const int qrl = qb * 32 + l31;

    unsigned short* const pbase  = &p_lds[0][0];
    unsigned short* const pwbase = pbase + qrl * 64 + h * 4;   // + buf*8192 + chunk

    // ---- prologue: tiles t0, t0+1: S + softmax -> buf0, buf1 ----
    f16x8 afA[8], afB[8]; s16x8 bfA[4], bfB[4];
#pragma unroll
    for (int kk = 0; kk < 8; ++kk) afA[kk] = *(const f16x8*)(Ap + (size_t)t0 * 8192 + kk * 512);
    {
        f32x16 s0 = 0.f, s1 = 0.f;
#pragma unroll
        for (int p = 0; p < 4; ++p) {
            s0 = __builtin_amdgcn_mfma_f32_32x32x16_f16(afA[2 * p],     qf[2 * p],     s0, 0, 0, 0);
            s1 = __builtin_amdgcn_mfma_f32_32x32x16_f16(afA[2 * p + 1], qf[2 * p + 1], s1, 0, 0, 0);
        }
        // B(t0) + A(t0+1): issue before softmax so latency hides under VALU.
#pragma unroll
        for (int kk = 0; kk < 4; ++kk) bfA[kk] = *(const s16x8*)(Bp + (size_t)t0 * 8192 + kk * 512);
#pragma unroll
        for (int kk = 0; kk < 8; ++kk) afB[kk] = *(const f16x8*)(Ap + (size_t)(t0 + 1) * 8192 + kk * 512);
        f32x16 sa = s0 + s1;
#pragma unroll
        for (int g = 0; g < 4; ++g)
            softmax4(sa[4 * g + 0], sa[4 * g + 1], sa[4 * g + 2], sa[4 * g + 3],
                     pwbase + (((kb * 4 + g) ^ x7) << 3), l_loc);
    }
    {
        // S(t0+1) from afB; then prefetch A(t0+2) into afA for iter 0.
        f32x16 s0 = 0.f, s1 = 0.f;
#pragma unroll
        for (int p = 0; p < 4; ++p) {
            s0 = __builtin_amdgcn_mfma_f32_32x32x16_f16(afB[2 * p],     qf[2 * p],     s0, 0, 0, 0);
            s1 = __builtin_amdgcn_mfma_f32_32x32x16_f16(afB[2 * p + 1], qf[2 * p + 1], s1, 0, 0, 0);
        }
#pragma unroll
        for (int kk = 0; kk < 8; ++kk) afA[kk] = *(const f16x8*)(Ap + (size_t)(t0 + 2) * 8192 + kk * 512);
        f32x16 sb = s0 + s1;
#pragma unroll
        for (int g = 0; g < 4; ++g)
            softmax4(sb[4 * g + 0], sb[4 * g + 1], sb[4 * g + 2], sb[4 * g + 3],
                     pwbase + 8192 + (((kb * 4 + g) ^ x7) << 3), l_loc);
    }
    __syncthreads();

    // ---- main loop: body count iters-2 (even). Iter it: af=A(it+2),
    // bf=B(it); loads A(it+3), B(it+1); reads P_it (buf it&3), writes
    // P_{it+2} (buf (it+2)&3). Barrier every 2 iters: produce->consume
    // distance 2 and buffer-reuse distance 4 both span >=1 barrier.
    const int npair = (iters - 2) >> 1;
    for (int p2 = 0; p2 < npair; ++p2) {
        const int it = p2 * 2;
        const int b  = (p2 & 1) << 1;               // it&3
        attn_iter(Ap, Bp, (size_t)(t0 + it + 3) * 8192, (size_t)(t0 + it + 1) * 8192,
                  afA, bfA, afB, bfB, qf,
                  pbase + (b << 13), pwbase + ((b ^ 2) << 13),
                  l31, h, x7, kb, l_loc, acc);
        attn_iter(Ap, Bp, (size_t)(t0 + it + 4) * 8192, (size_t)(t0 + it + 2) * 8192,
                  afB, bfB, afA, bfA, qf,
                  pbase + ((b ^ 1) << 13), pwbase + ((b ^ 3) << 13),
                  l31, h, x7, kb, l_loc, acc);
        __syncthreads();
    }
    // Note: the very last pair's A-prefetch reads tile t0+iters, which for
    // the last split overruns Kfp into KTp (valid memory, values unused).

    // ---- epilogue: PV for tiles iters-2 (bfA) and iters-1 (fresh load).
    // Both P-buffers were written before the final loop barrier.
    {
        s16x8 bfL[4];
#pragma unroll
        for (int kk = 0; kk < 4; ++kk)
            bfL[kk] = *(const s16x8*)(Bp + (size_t)(t0 + iters - 1) * 8192 + kk * 512);

        const unsigned short* pr2 = pbase + (size_t)(((iters - 2) & 3) << 13);
#pragma unroll
        for (int kk = 0; kk < 4; ++kk) {
            s16x8 ap[4];
            const int ch = ((kk * 2 + h) ^ x7) << 3;
#pragma unroll
            for (int qm = 0; qm < 4; ++qm)
                ap[qm] = *(const s16x8*)&pr2[(qm * 32 + l31) * 64 + ch];
#pragma unroll
            for (int qm = 0; qm < 4; ++qm)
                acc[qm] = __builtin_amdgcn_mfma_f32_32x32x16_bf16(ap[qm], bfA[kk], acc[qm], 0, 0, 0);
        }
        const unsigned short* pr3 = pbase + (size_t)(((iters - 1) & 3) << 13);
#pragma unroll
        for (int kk = 0; kk < 4; ++kk) {
            s16x8 ap[4];
            const int ch = ((kk * 2 + h) ^ x7) << 3;
#pragma unroll
            for (int qm = 0; qm < 4; ++qm)
                ap[qm] = *(const s16x8*)&pr3[(qm * 32 + l31) * 64 + ch];
#pragma unroll
            for (int qm = 0; qm < 4; ++qm)
                acc[qm] = __builtin_amdgcn_mfma_f32_32x32x16_bf16(ap[qm], bfL[kk], acc[qm], 0, 0, 0);
        }
    }

    // L partial: halves of each 32-key block via shfl, kb-fold via LDS.
    l_loc += __shfl_xor(l_loc, 32, 64);
    if (h == 0) l_red[kb][qb * 32 + l31] = l_loc;
    __syncthreads();
    if (tid < BM)
        Lp[(size_t)split * M_TOTAL + q0 + tid] = l_red[0][tid] + l_red[1][tid];

    // O partial: C/D col=l31 (d), row=(r&3)+8*(r>>2)+4h (q in qm*32 block).
    float* ob = (mat ? Ovp : Okp) + (size_t)split * (M_TOTAL * DDIM);
#pragma unroll
    for (int qm = 0; qm < 4; ++qm)
#pragma unroll
        for (int r = 0; r < 16; ++r) {
            int q = q0 + qm * 32 + (r & 3) + 8 * (r >> 2) + 4 * h;
            ob[(size_t)q * DDIM + dn * 32 + l31] = acc[qm][r];
        }
}

__global__ void combine_kernel(const float* __restrict__ Okp, const float* __restrict__ Ovp,
                               const float* __restrict__ Lp, float* __restrict__ out, int ns) {
    int i4 = blockIdx.x * 256 + threadIdx.x;        // float4 index, 131072 total
    int q  = i4 >> 5;
    float L = 0.f;
    float4 sk = make_float4(0.f, 0.f, 0.f, 0.f);
    float4 sv = make_float4(0.f, 0.f, 0.f, 0.f);
    for (int s = 0; s < ns; ++s) {
        L += Lp[(size_t)s * M_TOTAL + q];
        float4 a = ((const float4*)Okp)[(size_t)s * 131072 + i4];
        float4 b = ((const float4*)Ovp)[(size_t)s * 131072 + i4];
        sk.x += a.x; sk.y += a.y; sk.z += a.z; sk.w += a.w;
        sv.x += b.x; sv.y += b.y; sv.z += b.z; sv.w += b.w;
    }
    float inv = 1.f / L;
    float4 ok = make_float4(sk.x * inv, sk.y * inv, sk.z * inv, sk.w * inv);
    float4 ov = make_float4(sv.x * inv, sv.y * inv, sv.z * inv, sv.w * inv);
    ((float4*)out)[i4]          = ok;               // key_vectors
    ((float4*)out)[131072 + i4] = ov;               // value_vectors
}

extern "C" void kernel_launch(void* const* d_in, const int* in_sizes, int n_in,
                              void* d_out, int out_size, void* d_ws, size_t ws_size,
                              hipStream_t stream) {
    const float* Q = (const float*)d_in[0];
    const float* K = (const float*)d_in[1];
    const float* V = (const float*)d_in[2];
    float* out = (float*)d_out;

    // ws: Kfp 16MiB | KTp 16MiB | VTp 16MiB | Lp ns*16KB | Okp ns*2MiB | Ovp ns*2MiB
    const size_t MB = 1024 * 1024;
    int ns = 8, nslog = 3;
    while (ns > 2) {
        size_t need = 48 * MB + (size_t)ns * (4 * MB + 16384);
        if (need <= ws_size) break;
        ns >>= 1; nslog -= 1;
    }
    char* w0 = (char*)d_ws;
    _Float16*       Kfp = (_Float16*)w0;
    unsigned short* KTp = (unsigned short*)(w0 + 16 * MB);
    unsigned short* VTp = (unsigned short*)(w0 + 32 * MB);
    float*          Lp  = (float*)(w0 + 48 * MB);
    float*          Okp = (float*)(w0 + 48 * MB + (size_t)ns * 16384);
    float*          Ovp = Okp + (size_t)ns * (M_TOTAL * DDIM);

    prep_kernel<<<2048, 256, 0, stream>>>(K, V, Kfp, KTp, VTp);

    const int iters = 1024 / ns;                    // 64-key tiles per split
    attn_kernel<<<ns * 32, 512, 0, stream>>>(Q, Kfp, KTp, VTp, Okp, Ovp, Lp,
                                             iters, ns - 1, nslog);
    combine_kernel<<<(M_TOTAL * DDIM / 4) / 256, 256, 0, stream>>>(Okp, Ovp, Lp, out, ns);
}

// Round 6
// 294.600 us; speedup vs baseline: 1.6636x; 1.2364x over previous
//
#include <hip/hip_runtime.h>

// LaminiIndex v11: out_k = softmax(Q K^T) K, out_v = softmax(Q K^T) V
// Q: 4096x128 fp32, K/V: 65536x128 fp32, outputs fp32 concat.
//
// v8 (best, 215us attn): depth-2 P pipeline, barrier per 2 iters,
//   MfmaUtil 43%, 128V+64A = 192/256 regs.
// v9/v10 (FAILED): PV ds_read hoist spilled -- v9 via runtime pointer
//   (rule #20), v10 via raw register pressure (192 + 64 hoist > 256).
//   WRITE_SIZE inflation (36->341/62MB) is the spill signature.
// v11: register-neutral hoist. Drop the B-frag double-buffer (B(t) loaded
//   at top of iter t; first use is ~300cy later after ds_read issue + VMEM
//   issue + 8-MFMA S cluster, covering L2-warm latency) = -16 VGPR. Hoist
//   P chunks 0,1 (ap0/ap1, +32 VGPR), refill with chunks 2,3 after their
//   MFMA groups. Named arrays, constant indices only. ~160V + 64A = 224.

typedef _Float16 f16x8  __attribute__((ext_vector_type(8)));
typedef short    s16x8  __attribute__((ext_vector_type(8)));
typedef float    f32x16 __attribute__((ext_vector_type(16)));

#define M_TOTAL 4096
#define N_TOTAL 65536
#define DDIM    128
#define BM      128
#define BN      64

__device__ __forceinline__ unsigned int bf16_rne(float x) {
    unsigned int u = __float_as_uint(x);
    u += 0x7FFFu + ((u >> 16) & 1u);
    return u >> 16;
}

// One 64-key tile per block. K-blocks (bid<1024) write Kfp (S A-frags, f16)
// + KTp (O B-frags, bf16); V-blocks write VTp.
// Fragment order (32x32x16): A[m][k]: m=lane&31, k=8*(lane>>5)+j.
//                            B[k][n]: n=lane&31, k=8*(lane>>5)+j.
// Kfp slot c = (kb*8+kk)*64+lane  -> K[t*64+kb*32+(lane&31)][kk*16+8h+j]
// Tp  slot c = (dn*4+kk)*64+lane  -> X[t*64+kk*16+8h+j][dn*32+(lane&31)]
__global__ void prep_kernel(const float* __restrict__ K, const float* __restrict__ V,
                            _Float16* __restrict__ Kfp,
                            unsigned short* __restrict__ KTp,
                            unsigned short* __restrict__ VTp) {
    __shared__ float tile[64 * 132];
    const int bid = blockIdx.x;
    const int isV = bid >> 10;
    const int t   = bid & 1023;
    const float* src = isV ? V : K;
    const int tid = threadIdx.x;
#pragma unroll
    for (int k = 0; k < 8; ++k) {                   // 64x128 fp32 in, coalesced
        int c   = tid + 256 * k;
        int row = c >> 5;
        int c4  = c & 31;
        float4 v = *(const float4*)(src + (size_t)(t * 64 + row) * DDIM + c4 * 4);
        *(float4*)&tile[row * 132 + c4 * 4] = v;
    }
    __syncthreads();

    unsigned short* Tp = isV ? VTp : KTp;
#pragma unroll
    for (int r = 0; r < 4; ++r) {                   // B-frags: 1024 slots x 16B
        int c   = tid + 256 * r;
        int ln  = c & 63;
        int l31 = ln & 31, h = ln >> 5;
        int dn  = c >> 8;
        int kk  = (c >> 6) & 3;
        int col = dn * 32 + l31;                    // d
        int k0  = kk * 16 + h * 8;                  // key base
        uint4 o;
        o.x = bf16_rne(tile[(k0 + 0) * 132 + col]) | (bf16_rne(tile[(k0 + 1) * 132 + col]) << 16);
        o.y = bf16_rne(tile[(k0 + 2) * 132 + col]) | (bf16_rne(tile[(k0 + 3) * 132 + col]) << 16);
        o.z = bf16_rne(tile[(k0 + 4) * 132 + col]) | (bf16_rne(tile[(k0 + 5) * 132 + col]) << 16);
        o.w = bf16_rne(tile[(k0 + 6) * 132 + col]) | (bf16_rne(tile[(k0 + 7) * 132 + col]) << 16);
        *(uint4*)(Tp + ((size_t)t * 1024 + c) * 8) = o;
    }
    if (!isV) {
#pragma unroll
        for (int r = 0; r < 4; ++r) {               // A-frags: 1024 slots x 16B
            int c   = tid + 256 * r;
            int ln  = c & 63;
            int l31 = ln & 31, h = ln >> 5;
            int kb  = c >> 9;
            int kk  = (c >> 6) & 7;
            int row = kb * 32 + l31;                // key
            int d0  = kk * 16 + h * 8;
            f16x8 f;
#pragma unroll
            for (int j = 0; j < 8; ++j) f[j] = (_Float16)tile[row * 132 + d0 + j];
            *(f16x8*)(Kfp + ((size_t)t * 1024 + c) * 8) = f;
        }
    }
}

// exp(s-100) for 4 S values, pack to bf16 (RNE via v_cvt_pk), store 8B to LDS.
// l_loc accumulates the fp32 partial denominator.
__device__ __forceinline__ void softmax4(float s0, float s1, float s2, float s3,
                                         unsigned short* dst, float& l_loc) {
    const float L2E = 1.4426950408889634f;
    const float SH  = -144.26950408889634f;         // -100 * log2(e)
    float x0 = __builtin_fmaf(s0, L2E, SH);
    float x1 = __builtin_fmaf(s1, L2E, SH);
    float x2 = __builtin_fmaf(s2, L2E, SH);
    float x3 = __builtin_fmaf(s3, L2E, SH);
    float p0, p1, p2, p3;
    asm("v_exp_f32 %0, %1" : "=v"(p0) : "v"(x0));
    asm("v_exp_f32 %0, %1" : "=v"(p1) : "v"(x1));
    asm("v_exp_f32 %0, %1" : "=v"(p2) : "v"(x2));
    asm("v_exp_f32 %0, %1" : "=v"(p3) : "v"(x3));
    l_loc += (p0 + p1) + (p2 + p3);
    unsigned int r0, r1;
    asm("v_cvt_pk_bf16_f32 %0, %1, %2" : "=v"(r0) : "v"(p0), "v"(p1));
    asm("v_cvt_pk_bf16_f32 %0, %1, %2" : "=v"(r1) : "v"(p2), "v"(p3));
    uint2 pk; pk.x = r0; pk.y = r1;
    *(uint2*)dst = pk;
}

// One pipeline stage (iter t):
//   hoisted P_t ds_reads chunks 0,1 -> ap0/ap1 (latency hidden under the
//   VMEM issue burst + S cluster);
//   B(t) VMEM load (first use ~300cy later, L2-warm covers it);
//   A(t+3) VMEM prefetch;
//   S_{t+2} (two chains); 4 PV phases, refilling ap0/ap1 with chunks 2,3.
__device__ __forceinline__ void attn_iter(
    const _Float16* __restrict__ Ap, const unsigned short* __restrict__ Bp,
    size_t ta, size_t tb,
    f16x8 (&af)[8], f16x8 (&afn)[8],
    const f16x8 (&qf)[8],
    const unsigned short* __restrict__ pr, unsigned short* __restrict__ pw,
    int l31, int h, int x7, int kb, float& l_loc, f32x16 (&acc)[4])
{
    const int ch0 = ((0 + h) ^ x7) << 3;
    const int ch1 = ((2 + h) ^ x7) << 3;
    const int ch2 = ((4 + h) ^ x7) << 3;
    const int ch3 = ((6 + h) ^ x7) << 3;

    // Hoisted PV A-frag reads, chunks 0,1.
    s16x8 ap0[4], ap1[4];
#pragma unroll
    for (int qm = 0; qm < 4; ++qm)
        ap0[qm] = *(const s16x8*)&pr[(qm * 32 + l31) * 64 + ch0];
#pragma unroll
    for (int qm = 0; qm < 4; ++qm)
        ap1[qm] = *(const s16x8*)&pr[(qm * 32 + l31) * 64 + ch1];

    // B-frags for THIS tile (single-buffered: first use after S cluster).
    s16x8 bf[4];
#pragma unroll
    for (int kk = 0; kk < 4; ++kk) bf[kk] = *(const s16x8*)(Bp + tb + kk * 512);

    // A-frags for tile t+3 (consumed next iteration).
#pragma unroll
    for (int kk = 0; kk < 8; ++kk) afn[kk] = *(const f16x8*)(Ap + ta + kk * 512);

    // S_{t+2}: two interleaved dependency chains.
    f32x16 s0 = 0.f, s1 = 0.f;
    __builtin_amdgcn_s_setprio(1);
#pragma unroll
    for (int p = 0; p < 4; ++p) {
        s0 = __builtin_amdgcn_mfma_f32_32x32x16_f16(af[2 * p],     qf[2 * p],     s0, 0, 0, 0);
        s1 = __builtin_amdgcn_mfma_f32_32x32x16_f16(af[2 * p + 1], qf[2 * p + 1], s1, 0, 0, 0);
    }
    __builtin_amdgcn_s_setprio(0);
    f32x16 sn = s0 + s1;

    // ---- PV phase 0: consume ap0, refill ap0 <- chunk 2, softmax g0 ----
    __builtin_amdgcn_s_setprio(1);
#pragma unroll
    for (int qm = 0; qm < 4; ++qm)
        acc[qm] = __builtin_amdgcn_mfma_f32_32x32x16_bf16(ap0[qm], bf[0], acc[qm], 0, 0, 0);
    __builtin_amdgcn_s_setprio(0);
#pragma unroll
    for (int qm = 0; qm < 4; ++qm)
        ap0[qm] = *(const s16x8*)&pr[(qm * 32 + l31) * 64 + ch2];
    softmax4(sn[0], sn[1], sn[2], sn[3],
             pw + (((kb * 4 + 0) ^ x7) << 3), l_loc);

    // ---- PV phase 1: consume ap1, refill ap1 <- chunk 3, softmax g1 ----
    __builtin_amdgcn_s_setprio(1);
#pragma unroll
    for (int qm = 0; qm < 4; ++qm)
        acc[qm] = __builtin_amdgcn_mfma_f32_32x32x16_bf16(ap1[qm], bf[1], acc[qm], 0, 0, 0);
    __builtin_amdgcn_s_setprio(0);
#pragma unroll
    for (int qm = 0; qm < 4; ++qm)
        ap1[qm] = *(const s16x8*)&pr[(qm * 32 + l31) * 64 + ch3];
    softmax4(sn[4], sn[5], sn[6], sn[7],
             pw + (((kb * 4 + 1) ^ x7) << 3), l_loc);

    // ---- PV phase 2: consume ap0 (chunk 2), softmax g2 ----
    __builtin_amdgcn_s_setprio(1);
#pragma unroll
    for (int qm = 0; qm < 4; ++qm)
        acc[qm] = __builtin_amdgcn_mfma_f32_32x32x16_bf16(ap0[qm], bf[2], acc[qm], 0, 0, 0);
    __builtin_amdgcn_s_setprio(0);
    softmax4(sn[8], sn[9], sn[10], sn[11],
             pw + (((kb * 4 + 2) ^ x7) << 3), l_loc);

    // ---- PV phase 3: consume ap1 (chunk 3), softmax g3 ----
    __builtin_amdgcn_s_setprio(1);
#pragma unroll
    for (int qm = 0; qm < 4; ++qm)
        acc[qm] = __builtin_amdgcn_mfma_f32_32x32x16_bf16(ap1[qm], bf[3], acc[qm], 0, 0, 0);
    __builtin_amdgcn_s_setprio(0);
    softmax4(sn[12], sn[13], sn[14], sn[15],
             pw + (((kb * 4 + 3) ^ x7) << 3), l_loc);
}

// grid ns*32 (1-D), 512 thr. split = bid & (ns-1) -> same-XCD blocks share a
// key stream (L2 locality). Block: 128 queries x (1024/ns) 64-key tiles.
__global__ __launch_bounds__(512, 2)
void attn_kernel(const float* __restrict__ Q, const _Float16* __restrict__ Kfp,
                 const unsigned short* __restrict__ KTp, const unsigned short* __restrict__ VTp,
                 float* __restrict__ Okp, float* __restrict__ Ovp, float* __restrict__ Lp,
                 int iters, int nsm1, int nslog) {
    __shared__ unsigned short p_lds[4][BM * BN];    // P_t at buffer t&3, XOR-swizzled
    __shared__ float l_red[2][BM];

    const int bid   = blockIdx.x;
    const int split = bid & nsm1;
    const int q0    = (bid >> nslog) * BM;
    const int tid   = threadIdx.x;
    const int w     = tid >> 6;
    const int lane  = tid & 63;
    const int l31   = lane & 31;
    const int h     = lane >> 5;
    const int kb  = w & 1,  qb = w >> 1;            // S roles: key-half, q-quarter
    const int mat = w & 1,  dn = w >> 1;            // O roles: K/V, d-quarter

    // Q B-frags (loop-invariant): qf[kk][j] = Q[q0+qb*32+l31][kk*16+8h+j], f16.
    f16x8 qf[8];
    {
        const float* qrow = Q + (size_t)(q0 + qb * 32 + l31) * DDIM + h * 8;
#pragma unroll
        for (int kk = 0; kk < 8; ++kk) {
            float4 a = *(const float4*)(qrow + kk * 16);
            float4 b = *(const float4*)(qrow + kk * 16 + 4);
            f16x8 f;
            f[0] = (_Float16)a.x; f[1] = (_Float16)a.y; f[2] = (_Float16)a.z; f[3] = (_Float16)a.w;
            f[4] = (_Float16)b.x; f[5] = (_Float16)b.y; f[6] = (_Float16)b.z; f[7] = (_Float16)b.w;
            qf[kk] = f;
        }
    }

    const unsigned short* Tp = mat ? VTp : KTp;
    const _Float16*       Ap = Kfp + ((size_t)(kb * 8) * 64 + lane) * 8;   // + t*8192 + kk*512
    const unsigned short* Bp = Tp  + ((size_t)(dn * 4) * 64 + lane) * 8;   // + t*8192 + kk*512

    f32x16 acc[4];                                  // O: q128 x d32, one matrix
#pragma unroll
    for (int qm = 0; qm < 4; ++qm) acc[qm] = 0.f;
    float l_loc = 0.f;

    const int t0  = split * iters;
    const int x7  = l31 & 7;
    const int qrl = qb * 32 + l31;

    unsigned short* const pbase  = &p_lds[0][0];
    unsigned short* const pwbase = pbase + qrl * 64 + h * 4;   // + buf*8192 + chunk

    // ---- prologue: tiles t0, t0+1: S + softmax -> buf0, buf1 ----
    f16x8 afA[8], afB[8];
#pragma unroll
    for (int kk = 0; kk < 8; ++kk) afA[kk] = *(const f16x8*)(Ap + (size_t)t0 * 8192 + kk * 512);
    {
        f32x16 s0 = 0.f, s1 = 0.f;
#pragma unroll
        for (int p = 0; p < 4; ++p) {
            s0 = __builtin_amdgcn_mfma_f32_32x32x16_f16(afA[2 * p],     qf[2 * p],     s0, 0, 0, 0);
            s1 = __builtin_amdgcn_mfma_f32_32x32x16_f16(afA[2 * p + 1], qf[2 * p + 1], s1, 0, 0, 0);
        }
        // A(t0+1): issue before softmax so latency hides under VALU.
#pragma unroll
        for (int kk = 0; kk < 8; ++kk) afB[kk] = *(const f16x8*)(Ap + (size_t)(t0 + 1) * 8192 + kk * 512);
        f32x16 sa = s0 + s1;
#pragma unroll
        for (int g = 0; g < 4; ++g)
            softmax4(sa[4 * g + 0], sa[4 * g + 1], sa[4 * g + 2], sa[4 * g + 3],
                     pwbase + (((kb * 4 + g) ^ x7) << 3), l_loc);
    }
    {
        // S(t0+1) from afB; then prefetch A(t0+2) into afA for iter 0.
        f32x16 s0 = 0.f, s1 = 0.f;
#pragma unroll
        for (int p = 0; p < 4; ++p) {
            s0 = __builtin_amdgcn_mfma_f32_32x32x16_f16(afB[2 * p],     qf[2 * p],     s0, 0, 0, 0);
            s1 = __builtin_amdgcn_mfma_f32_32x32x16_f16(afB[2 * p + 1], qf[2 * p + 1], s1, 0, 0, 0);
        }
#pragma unroll
        for (int kk = 0; kk < 8; ++kk) afA[kk] = *(const f16x8*)(Ap + (size_t)(t0 + 2) * 8192 + kk * 512);
        f32x16 sb = s0 + s1;
#pragma unroll
        for (int g = 0; g < 4; ++g)
            softmax4(sb[4 * g + 0], sb[4 * g + 1], sb[4 * g + 2], sb[4 * g + 3],
                     pwbase + 8192 + (((kb * 4 + g) ^ x7) << 3), l_loc);
    }
    __syncthreads();

    // ---- main loop: body count iters-2 (even). Iter it: af=A(it+2);
    // loads A(it+3) and B(it); reads P_it (buf it&3), writes P_{it+2}
    // (buf (it+2)&3). Barrier every 2 iters: produce->consume distance 2
    // and buffer-reuse distance 4 both span >=1 barrier.
    const int npair = (iters - 2) >> 1;
    for (int p2 = 0; p2 < npair; ++p2) {
        const int it = p2 * 2;
        const int b  = (p2 & 1) << 1;               // it&3
        attn_iter(Ap, Bp, (size_t)(t0 + it + 3) * 8192, (size_t)(t0 + it) * 8192,
                  afA, afB, qf,
                  pbase + (b << 13), pwbase + ((b ^ 2) << 13),
                  l31, h, x7, kb, l_loc, acc);
        attn_iter(Ap, Bp, (size_t)(t0 + it + 4) * 8192, (size_t)(t0 + it + 1) * 8192,
                  afB, afA, qf,
                  pbase + ((b ^ 1) << 13), pwbase + ((b ^ 3) << 13),
                  l31, h, x7, kb, l_loc, acc);
        __syncthreads();
    }
    // Note: the very last pair's A-prefetch reads tile t0+iters, which for
    // the last split overruns Kfp into KTp (valid memory, values unused).

    // ---- epilogue: PV for tiles iters-2 and iters-1 (fresh B loads).
    // Both P-buffers were written before the final loop barrier.
    {
        s16x8 bfE[4], bfL[4];
#pragma unroll
        for (int kk = 0; kk < 4; ++kk)
            bfE[kk] = *(const s16x8*)(Bp + (size_t)(t0 + iters - 2) * 8192 + kk * 512);
#pragma unroll
        for (int kk = 0; kk < 4; ++kk)
            bfL[kk] = *(const s16x8*)(Bp + (size_t)(t0 + iters - 1) * 8192 + kk * 512);

        const unsigned short* pr2 = pbase + (size_t)(((iters - 2) & 3) << 13);
#pragma unroll
        for (int kk = 0; kk < 4; ++kk) {
            s16x8 ap[4];
            const int ch = ((kk * 2 + h) ^ x7) << 3;
#pragma unroll
            for (int qm = 0; qm < 4; ++qm)
                ap[qm] = *(const s16x8*)&pr2[(qm * 32 + l31) * 64 + ch];
#pragma unroll
            for (int qm = 0; qm < 4; ++qm)
                acc[qm] = __builtin_amdgcn_mfma_f32_32x32x16_bf16(ap[qm], bfE[kk], acc[qm], 0, 0, 0);
        }
        const unsigned short* pr3 = pbase + (size_t)(((iters - 1) & 3) << 13);
#pragma unroll
        for (int kk = 0; kk < 4; ++kk) {
            s16x8 ap[4];
            const int ch = ((kk * 2 + h) ^ x7) << 3;
#pragma unroll
            for (int qm = 0; qm < 4; ++qm)
                ap[qm] = *(const s16x8*)&pr3[(qm * 32 + l31) * 64 + ch];
#pragma unroll
            for (int qm = 0; qm < 4; ++qm)
                acc[qm] = __builtin_amdgcn_mfma_f32_32x32x16_bf16(ap[qm], bfL[kk], acc[qm], 0, 0, 0);
        }
    }

    // L partial: halves of each 32-key block via shfl, kb-fold via LDS.
    l_loc += __shfl_xor(l_loc, 32, 64);
    if (h == 0) l_red[kb][qb * 32 + l31] = l_loc;
    __syncthreads();
    if (tid < BM)
        Lp[(size_t)split * M_TOTAL + q0 + tid] = l_red[0][tid] + l_red[1][tid];

    // O partial: C/D col=l31 (d), row=(r&3)+8*(r>>2)+4h (q in qm*32 block).
    float* ob = (mat ? Ovp : Okp) + (size_t)split * (M_TOTAL * DDIM);
#pragma unroll
    for (int qm = 0; qm < 4; ++qm)
#pragma unroll
        for (int r = 0; r < 16; ++r) {
            int q = q0 + qm * 32 + (r & 3) + 8 * (r >> 2) + 4 * h;
            ob[(size_t)q * DDIM + dn * 32 + l31] = acc[qm][r];
        }
}

__global__ void combine_kernel(const float* __restrict__ Okp, const float* __restrict__ Ovp,
                               const float* __restrict__ Lp, float* __restrict__ out, int ns) {
    int i4 = blockIdx.x * 256 + threadIdx.x;        // float4 index, 131072 total
    int q  = i4 >> 5;
    float L = 0.f;
    float4 sk = make_float4(0.f, 0.f, 0.f, 0.f);
    float4 sv = make_float4(0.f, 0.f, 0.f, 0.f);
    for (int s = 0; s < ns; ++s) {
        L += Lp[(size_t)s * M_TOTAL + q];
        float4 a = ((const float4*)Okp)[(size_t)s * 131072 + i4];
        float4 b = ((const float4*)Ovp)[(size_t)s * 131072 + i4];
        sk.x += a.x; sk.y += a.y; sk.z += a.z; sk.w += a.w;
        sv.x += b.x; sv.y += b.y; sv.z += b.z; sv.w += b.w;
    }
    float inv = 1.f / L;
    float4 ok = make_float4(sk.x * inv, sk.y * inv, sk.z * inv, sk.w * inv);
    float4 ov = make_float4(sv.x * inv, sv.y * inv, sv.z * inv, sv.w * inv);
    ((float4*)out)[i4]          = ok;               // key_vectors
    ((float4*)out)[131072 + i4] = ov;               // value_vectors
}

extern "C" void kernel_launch(void* const* d_in, const int* in_sizes, int n_in,
                              void* d_out, int out_size, void* d_ws, size_t ws_size,
                              hipStream_t stream) {
    const float* Q = (const float*)d_in[0];
    const float* K = (const float*)d_in[1];
    const float* V = (const float*)d_in[2];
    float* out = (float*)d_out;

    // ws: Kfp 16MiB | KTp 16MiB | VTp 16MiB | Lp ns*16KB | Okp ns*2MiB | Ovp ns*2MiB
    const size_t MB = 1024 * 1024;
    int ns = 8, nslog = 3;
    while (ns > 2) {
        size_t need = 48 * MB + (size_t)ns * (4 * MB + 16384);
        if (need <= ws_size) break;
        ns >>= 1; nslog -= 1;
    }
    char* w0 = (char*)d_ws;
    _Float16*       Kfp = (_Float16*)w0;
    unsigned short* KTp = (unsigned short*)(w0 + 16 * MB);
    unsigned short* VTp = (unsigned short*)(w0 + 32 * MB);
    float*          Lp  = (float*)(w0 + 48 * MB);
    float*          Okp = (float*)(w0 + 48 * MB + (size_t)ns * 16384);
    float*          Ovp = Okp + (size_t)ns * (M_TOTAL * DDIM);

    prep_kernel<<<2048, 256, 0, stream>>>(K, V, Kfp, KTp, VTp);

    const int iters = 1024 / ns;                    // 64-key tiles per split
    attn_kernel<<<ns * 32, 512, 0, stream>>>(Q, Kfp, KTp, VTp, Okp, Ovp, Lp,
                                             iters, ns - 1, nslog);
    combine_kernel<<<(M_TOTAL * DDIM / 4) / 256, 256, 0, stream>>>(Okp, Ovp, Lp, out, ns);
}